// Round 16
// baseline (1249.292 us; speedup 1.0000x reference)
//
#include <hip/hip_runtime.h>

typedef unsigned short u16;
typedef __attribute__((ext_vector_type(8))) short short8;
typedef __attribute__((ext_vector_type(4))) short s16x4;
typedef __attribute__((ext_vector_type(4))) float f32x4;

__device__ inline u16 f2bf(float f){
  unsigned int u = __builtin_bit_cast(unsigned int, f);
  u += 0x7fffu + ((u >> 16) & 1u);
  return (u16)(u >> 16);
}
__device__ inline float bf2f(u16 h){
  unsigned int u = ((unsigned int)h) << 16;
  return __builtin_bit_cast(float, u);
}

typedef __attribute__((address_space(1))) const void* as1_t;
typedef __attribute__((address_space(3))) void* as3_t;
__device__ __forceinline__ void gload16(const u16* g, u16* l) {
  __builtin_amdgcn_global_load_lds((as1_t)g, (as3_t)l, 16, 0, 0);
}

#define BARRIER() asm volatile("s_barrier" ::: "memory")
#define VMCNT4()  asm volatile("s_waitcnt vmcnt(4)" ::: "memory")
#define VMCNT0()  asm volatile("s_waitcnt vmcnt(0)" ::: "memory")
#define LGKM0()   asm volatile("s_waitcnt lgkmcnt(0)" ::: "memory")

// ================= shared 8-phase GEMM core (R8-verified: 0 bank conflicts) ==
__device__ __forceinline__ void gemm_core(
    const u16* __restrict__ A, const u16* __restrict__ B, u16* __restrict__ C,
    int tile_m, int tile_n, int abase, int hoff,
    int M, int K, int lda, int ldb, int ldc, u16* lds)
{
  int tid = threadIdx.x, wave = tid >> 6, lane = tid & 63;
  int wm = wave >> 2, wn = wave & 3;
  int NT = K >> 6;

  const u16* sA[2]; const u16* sB[2];
  int dq[2];
#pragma unroll
  for (int q = 0; q < 2; ++q) {
    int row = q * 128 + (tid >> 2);
    int cg  = (tid & 3) ^ ((row >> 1) & 3);
    sA[q] = A + (size_t)(abase + row) * lda + hoff + cg * 8;
    sB[q] = B + (size_t)(tile_n + row) * ldb + hoff + cg * 8;
    dq[q] = q * 4096 + tid * 8;
  }

  int l15 = lane & 15, c4 = lane >> 4;
  int aoff[8], boff[4];
#pragma unroll
  for (int mi = 0; mi < 8; ++mi) {
    int r = wm * 128 + mi * 16 + l15;
    aoff[mi] = r * 32 + ((c4 ^ ((r >> 1) & 3)) * 8);
  }
#pragma unroll
  for (int ni = 0; ni < 4; ++ni) {
    int r = wn * 64 + ni * 16 + l15;
    boff[ni] = r * 32 + ((c4 ^ ((r >> 1) & 3)) * 8);
  }

  f32x4 acc[8][4];
#pragma unroll
  for (int mi = 0; mi < 8; ++mi)
#pragma unroll
    for (int ni = 0; ni < 4; ++ni) { f32x4 z = {0.f,0.f,0.f,0.f}; acc[mi][ni] = z; }

#define DSRA(fa, mb, base) \
  fa[0] = *reinterpret_cast<const short8*>(&lds[(base) + aoff[(mb)+0]]); \
  fa[1] = *reinterpret_cast<const short8*>(&lds[(base) + aoff[(mb)+1]]); \
  fa[2] = *reinterpret_cast<const short8*>(&lds[(base) + aoff[(mb)+2]]); \
  fa[3] = *reinterpret_cast<const short8*>(&lds[(base) + aoff[(mb)+3]]);
#define DSRB(fb, base) \
  fb[0] = *reinterpret_cast<const short8*>(&lds[(base) + boff[0]]); \
  fb[1] = *reinterpret_cast<const short8*>(&lds[(base) + boff[1]]); \
  fb[2] = *reinterpret_cast<const short8*>(&lds[(base) + boff[2]]); \
  fb[3] = *reinterpret_cast<const short8*>(&lds[(base) + boff[3]]);
#define MM16(mb, fa, fb) \
  _Pragma("unroll") for (int mi = 0; mi < 4; ++mi) \
  _Pragma("unroll") for (int ni = 0; ni < 4; ++ni) \
    acc[(mb)+mi][ni] = __builtin_amdgcn_mfma_f32_16x16x32_bf16(fa[mi], fb[ni], acc[(mb)+mi][ni], 0, 0, 0);
#define PH_SYNC() BARRIER(); LGKM0(); __builtin_amdgcn_sched_barrier(0)
#define PRIO1() __builtin_amdgcn_s_setprio(1)
#define PRIO0() __builtin_amdgcn_s_setprio(0)

#pragma unroll
  for (int q = 0; q < 2; ++q) {
    gload16(sA[q],      &lds[0     + dq[q]]);
    gload16(sB[q],      &lds[16384 + dq[q]]);
    gload16(sA[q] + 32, &lds[8192  + dq[q]]);
    gload16(sB[q] + 32, &lds[24576 + dq[q]]);
  }
  VMCNT0();
  BARRIER();

  for (int t = 0; t < NT; ++t) {
    int cb = (t & 1) * 32768;
    int nb = cb ^ 32768;
    bool st = (t + 1) < NT;
    int ke = (t + 1) * 64;
    short8 fa[4], fb0[4], fb1[4];
    DSRA(fa, 0, cb + 0);
    DSRB(fb0, cb + 16384);
    if (st) { gload16(sA[0] + ke, &lds[nb + dq[0]]);
              gload16(sA[1] + ke, &lds[nb + dq[1]]); }
    PH_SYNC(); PRIO1(); MM16(0, fa, fb0); PRIO0();
    BARRIER();
    DSRA(fa, 4, cb + 0);
    if (st) { gload16(sB[0] + ke, &lds[nb + 16384 + dq[0]]);
              gload16(sB[1] + ke, &lds[nb + 16384 + dq[1]]); }
    PH_SYNC(); PRIO1(); MM16(4, fa, fb0); PRIO0();
    if (st) { VMCNT4(); } else { VMCNT0(); }
    BARRIER();
    DSRA(fa, 0, cb + 8192);
    DSRB(fb1, cb + 24576);
    if (st) { gload16(sA[0] + ke + 32, &lds[nb + 8192 + dq[0]]);
              gload16(sA[1] + ke + 32, &lds[nb + 8192 + dq[1]]); }
    PH_SYNC(); PRIO1(); MM16(0, fa, fb1); PRIO0();
    BARRIER();
    DSRA(fa, 4, cb + 8192);
    if (st) { gload16(sB[0] + ke + 32, &lds[nb + 24576 + dq[0]]);
              gload16(sB[1] + ke + 32, &lds[nb + 24576 + dq[1]]); }
    PH_SYNC(); PRIO1(); MM16(4, fa, fb1); PRIO0();
    if (st) { VMCNT4(); }
    BARRIER();
  }

  int rq = (lane >> 4) * 4;
#pragma unroll
  for (int mi = 0; mi < 8; ++mi)
#pragma unroll
    for (int ni = 0; ni < 4; ++ni) {
      int col = tile_n + wn * 64 + ni * 16 + l15;
#pragma unroll
      for (int j = 0; j < 4; ++j) {
        int row = tile_m + wm * 128 + mi * 16 + rq + j;
        if (row < M) C[(size_t)row * ldc + col] = f2bf(acc[mi][ni][j]);
      }
    }
#undef DSRA
#undef DSRB
#undef MM16
#undef PH_SYNC
#undef PRIO1
#undef PRIO0
}

// GEMM wrapper; headed=1 remaps A rows/K-cols per 2048-sized head blocks
__global__ __launch_bounds__(512, 2) void gemm8p(
    const u16* __restrict__ A, const u16* __restrict__ B, u16* __restrict__ C,
    int M, int N, int K, int lda, int ldb, int ldc, int headed)
{
  __shared__ alignas(16) u16 lds[65536];
  int tile_m = blockIdx.y * 256, tile_n = blockIdx.x * 256;
  int hoff  = headed ? ((tile_m >> 11) << 11) : 0;
  int abase = headed ? (tile_m & 2047) : tile_m;
  gemm_core(A, B, C, tile_m, tile_n, abase, hoff, M, K, lda, ldb, ldc, lds);
}

// batched 2-job headed U-GEMM (tail-merge): job0 N0 (s1 blocks), job1 N1.
// Both: M=8192, K=2048, lda=ldb=8192, headed input, plain C (ldc=Nj).
__global__ __launch_bounds__(512, 2) void gemm8p_u2(
    const u16* A0, const u16* B0, u16* C0, int N0,
    const u16* A1, const u16* B1, u16* C1, int N1, int s1)
{
  __shared__ alignas(16) u16 lds[65536];
  int flat = blockIdx.x;
  int j = flat >= s1;
  const u16* A = j ? A1 : A0;
  const u16* B = j ? B1 : B0;
  u16*       C = j ? C1 : C0;
  int N = j ? N1 : N0;
  int lbx = flat - (j ? s1 : 0);
  int ntile = N >> 8;
  int tile_n = (lbx % ntile) * 256;
  int tile_m = (lbx / ntile) * 256;
  gemm_core(A, B, C, tile_m, tile_n, tile_m & 2047, (tile_m >> 11) << 11,
            8192, 2048, 8192, 8192, N, lds);
}

// ---------------- prep_w: W f32 -> Wb bf16 AND wsd score table ---------------
__global__ __launch_bounds__(256) void prep_w(
    const float* __restrict__ W, u16* __restrict__ Wb,
    const float* __restrict__ asrc, const float* __restrict__ adst,
    float* __restrict__ wsd, int Fin, int Fp)
{
  int f = blockIdx.x;
  int w = threadIdx.x >> 6, lane = threadIdx.x & 63;
  if (f >= Fin) {   // zero-pad row (L0: rows 300..511)
    s16x4 z = {0,0,0,0};
#pragma unroll
    for (int i = 0; i < 8; ++i)
      *reinterpret_cast<s16x4*>(Wb + (size_t)f * 8192 + w * 2048 + lane * 4 + i * 256) = z;
    if (lane == 0) { wsd[w * Fp + f] = 0.f; wsd[(4 + w) * Fp + f] = 0.f; }
    return;
  }
  const float* wr = W + (size_t)f * 8192 + w * 2048;
  const float* as = asrc + w * 2048;
  const float* ad = adst + w * 2048;
  u16* wb = Wb + (size_t)f * 8192 + w * 2048;
  float ss = 0.f, dd = 0.f;
#pragma unroll
  for (int i = 0; i < 8; ++i) {
    int c = lane * 4 + i * 256;
    f32x4 wv = *reinterpret_cast<const f32x4*>(wr + c);
    f32x4 av = *reinterpret_cast<const f32x4*>(as + c);
    f32x4 dv = *reinterpret_cast<const f32x4*>(ad + c);
    s16x4 ov;
#pragma unroll
    for (int j = 0; j < 4; ++j) {
      ss += wv[j] * av[j]; dd += wv[j] * dv[j];
      ov[j] = (short)f2bf(wv[j]);
    }
    *reinterpret_cast<s16x4*>(wb + c) = ov;
  }
  for (int off = 32; off; off >>= 1) {
    ss += __shfl_down(ss, off);
    dd += __shfl_down(dd, off);
  }
  if (lane == 0) { wsd[w * Fp + f] = ss; wsd[(4 + w) * Fp + f] = dd; }
}

// ------- transpose_bias: Wh[8192,2048] -> Wht[2048,8192] + atomic bc-fold ----
__global__ __launch_bounds__(256) void transpose_bias(
    const float* __restrict__ Wh, u16* __restrict__ Wht,
    const float* __restrict__ bc, float* __restrict__ bhp)
{
  __shared__ float tile[32][33];
  int k0 = blockIdx.x * 32, n0 = blockIdx.y * 32;
  int tx = threadIdx.x & 31, ty = threadIdx.x >> 5;
#pragma unroll
  for (int i = 0; i < 4; ++i)
    tile[ty + i * 8][tx] = Wh[(size_t)(k0 + ty + i * 8) * 2048 + n0 + tx];
  __syncthreads();
#pragma unroll
  for (int i = 0; i < 4; ++i)
    Wht[(size_t)(n0 + ty + i * 8) * 8192 + k0 + tx] = f2bf(tile[tx][ty + i * 8]);
  if (threadIdx.x < 32) {
    float p = 0.f;
#pragma unroll
    for (int kk = 0; kk < 32; ++kk) p += bc[k0 + kk] * tile[kk][threadIdx.x];
    atomicAdd(&bhp[n0 + threadIdx.x], p);
  }
}

__global__ void init_bhp(const float* b0, const float* b1, const float* b2,
                         float* bhp){
  int i = blockIdx.x * 256 + threadIdx.x;
  int l = blockIdx.y;
  if (i < 2048) {
    const float* s = (l == 0) ? b0 : (l == 1 ? b1 : b2);
    bhp[l * 2048 + i] = s[i];
  }
}

// ---------------- transpose_cast (MLP weights) -------------------------------
__global__ __launch_bounds__(256) void transpose_cast(
    const float* __restrict__ W, u16* __restrict__ Wt, int K, int N, int Kpad)
{
  __shared__ float tile[32][33];
  int k0 = blockIdx.x * 32, n0 = blockIdx.y * 32;
  int tx = threadIdx.x & 31, ty = threadIdx.x >> 5;
#pragma unroll
  for (int i = 0; i < 4; ++i) {
    int k = k0 + ty + i * 8;
    float v = 0.f;
    if (k < K && (n0 + tx) < N) v = W[(size_t)k * N + n0 + tx];
    tile[ty + i * 8][tx] = v;
  }
  __syncthreads();
#pragma unroll
  for (int i = 0; i < 4; ++i) {
    int nn = n0 + ty + i * 8;
    if (nn < N) Wt[(size_t)nn * Kpad + k0 + tx] = f2bf(tile[tx][ty + i * 8]);
  }
}

// ---------------- cast with col padding --------------------------------------
__global__ void cast_pad(const float* __restrict__ x, u16* __restrict__ xb,
                         int R, int C, int Cp)
{
  int i = blockIdx.x * 256 + threadIdx.x;
  if (i >= R * Cp) return;
  int r = i / Cp, c = i % Cp;
  xb[i] = f2bf(c < C ? x[(size_t)r * C + c] : 0.f);
}

// ---------------- a_score (layer 0 only) -------------------------------------
__global__ __launch_bounds__(256) void a_score(
    const u16* __restrict__ xb, const float* __restrict__ wsd,
    float* __restrict__ a_s, float* __restrict__ a_d, int Fp)
{
  int n = blockIdx.x, tid = threadIdx.x, lane = tid & 63, w = tid >> 6;
  float s[4] = {0.f,0.f,0.f,0.f}, d[4] = {0.f,0.f,0.f,0.f};
  int f = tid * 8;
  if (f < Fp) {
    short8 v = *reinterpret_cast<const short8*>(xb + (size_t)n * Fp + f);
#pragma unroll
    for (int j = 0; j < 8; ++j) {
      float xv = bf2f((u16)v[j]);
#pragma unroll
      for (int h = 0; h < 4; ++h) {
        s[h] += xv * wsd[h * Fp + f + j];
        d[h] += xv * wsd[(4 + h) * Fp + f + j];
      }
    }
  }
  __shared__ float red[4][8];
#pragma unroll
  for (int h = 0; h < 4; ++h) {
    for (int off = 32; off; off >>= 1) {
      s[h] += __shfl_down(s[h], off);
      d[h] += __shfl_down(d[h], off);
    }
  }
  if (lane == 0) {
#pragma unroll
    for (int h = 0; h < 4; ++h) { red[w][h] = s[h]; red[w][4 + h] = d[h]; }
  }
  __syncthreads();
  if (tid < 8) {
    float t = red[0][tid] + red[1][tid] + red[2][tid] + red[3][tid];
    if (tid < 4) a_s[n * 4 + tid] = t;
    else         a_d[n * 4 + tid - 4] = t;
  }
}

// ---------------- CSR build --------------------------------------------------
__global__ void zero_int(int* p, int n){ int i = blockIdx.x*256+threadIdx.x; if (i < n) p[i] = 0; }

__global__ void count_deg(const int* __restrict__ ei, int E, int Nn, int* __restrict__ deg){
  int e = blockIdx.x*256+threadIdx.x; if (e >= E + Nn) return;
  int d = (e < E) ? ei[E + e] : (e - E);
  atomicAdd(&deg[d], 1);
}

__global__ void scan_deg(const int* __restrict__ deg, int* __restrict__ row_st,
                         int* __restrict__ cursor, int Nn){
  __shared__ int partial[256];
  int tid = threadIdx.x;
  int chunk = (Nn + 255) / 256;
  int start = tid * chunk;
  int sum = 0;
  for (int i = 0; i < chunk; ++i) { int idx = start + i; if (idx < Nn) sum += deg[idx]; }
  partial[tid] = sum;
  __syncthreads();
  if (tid == 0) { int acc = 0; for (int i = 0; i < 256; ++i) { int t = partial[i]; partial[i] = acc; acc += t; } }
  __syncthreads();
  int acc = partial[tid];
  for (int i = 0; i < chunk; ++i) {
    int idx = start + i;
    if (idx < Nn) { row_st[idx] = acc; cursor[idx] = acc; acc += deg[idx]; }
  }
  if (tid == 255) row_st[Nn] = acc;
}

__global__ void scatter_edges(const int* __restrict__ ei, int E, int Nn,
                              int* __restrict__ cursor, int* __restrict__ srcs){
  int e = blockIdx.x*256+threadIdx.x; if (e >= E + Nn) return;
  int s = (e < E) ? ei[e]     : (e - E);
  int d = (e < E) ? ei[E + e] : (e - E);
  int pos = atomicAdd(&cursor[d], 1);
  srcs[pos] = s;
}

// ---------------- per-(node,head) edge softmax -------------------------------
__global__ void edge_softmax(const int* __restrict__ row_st, const int* __restrict__ srcs,
                             const float* __restrict__ a_s, const float* __restrict__ a_d,
                             float* __restrict__ alpha, int Nn){
  int t = blockIdx.x*256+threadIdx.x;
  if (t >= Nn * 4) return;
  int n = t >> 2, hh = t & 3;
  int b = row_st[n], e = row_st[n + 1];
  float ad = a_d[n * 4 + hh];
  float m = -1e30f;
  for (int p = b; p < e; ++p) {
    float x = a_s[srcs[p] * 4 + hh] + ad;
    x = x > 0.f ? x : 0.2f * x;
    alpha[p * 4 + hh] = x;
    m = fmaxf(m, x);
  }
  float ssum = 0.f;
  for (int p = b; p < e; ++p) {
    float ex = expf(alpha[p * 4 + hh] - m);
    alpha[p * 4 + hh] = ex;
    ssum += ex;
  }
  float inv = 1.f / (ssum + 1e-16f);
  for (int p = b; p < e; ++p) alpha[p * 4 + hh] *= inv;
}

// -------- aggregate2: grid (Nn, 2), 256 thr, prefetch distance 2 -------------
// out[n,c] = act( sum_h sum_e alpha*z[src,h*2048+c] + bhp[c] ), c in half*1024..
// per-thread accumulation order identical to R14/R15 (deterministic).
__global__ __launch_bounds__(256) void aggregate2(
    const u16* __restrict__ z, const float* __restrict__ alpha,
    const int* __restrict__ row_st, const int* __restrict__ srcs,
    const float* __restrict__ bhp, u16* __restrict__ out, int relu,
    const float* __restrict__ wsd_next, float* __restrict__ psum)
{
  int n = blockIdx.x, half = blockIdx.y, tid = threadIdx.x;
  int c = half * 1024 + tid * 4;
  float acc[4] = {0.f, 0.f, 0.f, 0.f};
  int b = row_st[n], e = row_st[n + 1];         // e > b (self-loop)

  // 2-deep edge pipeline: cur = edge p, nxt = edge p+1, issue p+2 early.
  int s0 = srcs[b];
  const u16* zr = z + (size_t)s0 * 8192 + c;
  s16x4 cv0 = *reinterpret_cast<const s16x4*>(zr);
  s16x4 cv1 = *reinterpret_cast<const s16x4*>(zr + 2048);
  s16x4 cv2 = *reinterpret_cast<const s16x4*>(zr + 4096);
  s16x4 cv3 = *reinterpret_cast<const s16x4*>(zr + 6144);
  float ca0 = alpha[b * 4 + 0], ca1 = alpha[b * 4 + 1];
  float ca2 = alpha[b * 4 + 2], ca3 = alpha[b * 4 + 3];
  s16x4 nv0, nv1, nv2, nv3;
  float na0 = 0.f, na1 = 0.f, na2 = 0.f, na3 = 0.f;
  if (b + 1 < e) {
    int s1 = srcs[b + 1];
    const u16* zr1 = z + (size_t)s1 * 8192 + c;
    nv0 = *reinterpret_cast<const s16x4*>(zr1);
    nv1 = *reinterpret_cast<const s16x4*>(zr1 + 2048);
    nv2 = *reinterpret_cast<const s16x4*>(zr1 + 4096);
    nv3 = *reinterpret_cast<const s16x4*>(zr1 + 6144);
    na0 = alpha[(b + 1) * 4 + 0]; na1 = alpha[(b + 1) * 4 + 1];
    na2 = alpha[(b + 1) * 4 + 2]; na3 = alpha[(b + 1) * 4 + 3];
  }

  for (int p = b; p < e; ++p) {
    s16x4 w0 = cv0, w1 = cv1, w2 = cv2, w3 = cv3;
    float b0 = ca0, b1 = ca1, b2 = ca2, b3 = ca3;
    cv0 = nv0; cv1 = nv1; cv2 = nv2; cv3 = nv3;
    ca0 = na0; ca1 = na1; ca2 = na2; ca3 = na3;
    if (p + 2 < e) {                            // issue edge p+2's loads early
      int s2 = srcs[p + 2];
      const u16* zr2 = z + (size_t)s2 * 8192 + c;
      nv0 = *reinterpret_cast<const s16x4*>(zr2);
      nv1 = *reinterpret_cast<const s16x4*>(zr2 + 2048);
      nv2 = *reinterpret_cast<const s16x4*>(zr2 + 4096);
      nv3 = *reinterpret_cast<const s16x4*>(zr2 + 6144);
      na0 = alpha[(p + 2) * 4 + 0]; na1 = alpha[(p + 2) * 4 + 1];
      na2 = alpha[(p + 2) * 4 + 2]; na3 = alpha[(p + 2) * 4 + 3];
    }
#pragma unroll
    for (int q = 0; q < 4; ++q)
      acc[q] += b0 * bf2f((u16)w0[q]) + b1 * bf2f((u16)w1[q])
              + b2 * bf2f((u16)w2[q]) + b3 * bf2f((u16)w3[q]);
  }

  float sv[4] = {0.f,0.f,0.f,0.f}, dv[4] = {0.f,0.f,0.f,0.f};
  s16x4 ov;
#pragma unroll
  for (int q = 0; q < 4; ++q) {
    float v = acc[q] + bhp[c + q];
    if (relu) v = fmaxf(v, 0.f);
    ov[q] = (short)f2bf(v);
    if (wsd_next) {
#pragma unroll
      for (int h = 0; h < 4; ++h) {
        sv[h] += v * wsd_next[h * 2048 + c + q];
        dv[h] += v * wsd_next[(4 + h) * 2048 + c + q];
      }
    }
  }
  *reinterpret_cast<s16x4*>(out + (size_t)n * 2048 + c) = ov;
  if (wsd_next) {
    int lane = tid & 63, w = tid >> 6;          // 4 waves
    __shared__ float red[4][8];
#pragma unroll
    for (int h = 0; h < 4; ++h) {
      for (int off = 32; off; off >>= 1) {
        sv[h] += __shfl_down(sv[h], off);
        dv[h] += __shfl_down(dv[h], off);
      }
    }
    if (lane == 0) {
#pragma unroll
      for (int h = 0; h < 4; ++h) { red[w][h] = sv[h]; red[w][4 + h] = dv[h]; }
    }
    __syncthreads();
    if (tid < 8) {
      float t = red[0][tid] + red[1][tid] + red[2][tid] + red[3][tid];
      psum[(size_t)n * 16 + half * 8 + tid] = t;
    }
  }
}

// -------- combine partial scores: a_s/a_d[n,h] = psum halves summed ----------
__global__ void combine_scores(const float* __restrict__ psum,
                               float* __restrict__ a_s, float* __restrict__ a_d,
                               int Nn){
  int i = blockIdx.x * 256 + threadIdx.x;
  if (i >= Nn * 4) return;
  int n = i >> 2, h = i & 3;
  a_s[i] = psum[(size_t)n * 16 + h]     + psum[(size_t)n * 16 + 8 + h];
  a_d[i] = psum[(size_t)n * 16 + 4 + h] + psum[(size_t)n * 16 + 12 + h];
}

// ---------------- mean pool over sorted batch --------------------------------
__global__ __launch_bounds__(256) void pool_mean(
    const u16* __restrict__ hf, const int* __restrict__ batch,
    u16* __restrict__ g, int Nn)
{
  int gid = blockIdx.x, tid = threadIdx.x;
  int s1, s2;
  { int l = 0, h = Nn; while (l < h) { int m = (l + h) >> 1; if (batch[m] < gid) l = m + 1; else h = m; } s1 = l; }
  { int l = 0, h = Nn; while (l < h) { int m = (l + h) >> 1; if (batch[m] < gid + 1) l = m + 1; else h = m; } s2 = l; }
  float inv = 1.f / fmaxf((float)(s2 - s1), 1.f);
  float acc[8];
#pragma unroll
  for (int q = 0; q < 8; ++q) acc[q] = 0.f;
  for (int r = s1; r < s2; ++r) {
    short8 v = *reinterpret_cast<const short8*>(hf + (size_t)r * 2048 + tid * 8);
#pragma unroll
    for (int q = 0; q < 8; ++q) acc[q] += bf2f((u16)v[q]);
  }
  short8 ov;
#pragma unroll
  for (int q = 0; q < 8; ++q) ov[q] = (short)f2bf(acc[q] * inv);
  *reinterpret_cast<short8*>(g + (size_t)gid * 2048 + tid * 8) = ov;
}

// ---------------- 128x128 GEMM (R2 structure; MLP GEMMs) ---------------------
__global__ __launch_bounds__(256) void gemm_bt(
    const u16* __restrict__ A, const u16* __restrict__ B,
    float* __restrict__ Cf, u16* __restrict__ Cb,
    const float* __restrict__ bias, int M, int N, int K, int relu)
{
  __shared__ alignas(16) u16 As[128 * 32];
  __shared__ alignas(16) u16 Bs[128 * 32];
  int tid = threadIdx.x;
  int wave = tid >> 6, lane = tid & 63;
  int wr = wave >> 1, wc = wave & 1;
  int tile_m = blockIdx.y * 128, tile_n = blockIdx.x * 128;

  int sr = wave * 16 + (lane >> 2);
  int sc = (lane & 3) * 8;
  const u16* gA0 = A + (size_t)(tile_m + sr) * K + sc;
  const u16* gA1 = A + (size_t)(tile_m + 64 + sr) * K + sc;
  const u16* gB0 = B + (size_t)(tile_n + sr) * K + sc;
  const u16* gB1 = B + (size_t)(tile_n + 64 + sr) * K + sc;
  u16* lA0 = &As[wave * 512];
  u16* lA1 = &As[2048 + wave * 512];
  u16* lB0 = &Bs[wave * 512];
  u16* lB1 = &Bs[2048 + wave * 512];

  f32x4 acc[4][4];
#pragma unroll
  for (int mi = 0; mi < 4; ++mi)
#pragma unroll
    for (int ni = 0; ni < 4; ++ni) { f32x4 z = {0.f,0.f,0.f,0.f}; acc[mi][ni] = z; }

  int lrow = lane & 15, lk = (lane >> 4) * 8;

  for (int k0 = 0; k0 < K; k0 += 32) {
    gload16(gA0 + k0, lA0);
    gload16(gA1 + k0, lA1);
    gload16(gB0 + k0, lB0);
    gload16(gB1 + k0, lB1);
    __syncthreads();
    short8 af[4], bfr[4];
#pragma unroll
    for (int mi = 0; mi < 4; ++mi)
      af[mi] = *reinterpret_cast<const short8*>(&As[(wr * 64 + mi * 16 + lrow) * 32 + lk]);
#pragma unroll
    for (int ni = 0; ni < 4; ++ni)
      bfr[ni] = *reinterpret_cast<const short8*>(&Bs[(wc * 64 + ni * 16 + lrow) * 32 + lk]);
#pragma unroll
    for (int mi = 0; mi < 4; ++mi)
#pragma unroll
      for (int ni = 0; ni < 4; ++ni)
        acc[mi][ni] = __builtin_amdgcn_mfma_f32_16x16x32_bf16(af[mi], bfr[ni], acc[mi][ni], 0, 0, 0);
    __syncthreads();
  }

  int rquad = (lane >> 4) * 4;
#pragma unroll
  for (int mi = 0; mi < 4; ++mi)
#pragma unroll
    for (int ni = 0; ni < 4; ++ni) {
      int col = tile_n + wc * 64 + ni * 16 + lrow;
      float bv = bias ? bias[col] : 0.f;
#pragma unroll
      for (int j = 0; j < 4; ++j) {
        int row = tile_m + wr * 64 + mi * 16 + rquad + j;
        if (row < M) {
          float v = acc[mi][ni][j] + bv;
          if (relu) v = fmaxf(v, 0.f);
          if (Cb) Cb[(size_t)row * N + col] = f2bf(v);
          else    Cf[(size_t)row * N + col] = v;
        }
      }
    }
}

// ---------------- layernorm over 768 ----------------------------------------
__global__ __launch_bounds__(256) void layernorm_768(
    const float* __restrict__ x, const float* __restrict__ gam,
    const float* __restrict__ bet, float* __restrict__ out)
{
  int row = blockIdx.x, tid = threadIdx.x, lane = tid & 63, w = tid >> 6;
  __shared__ float sh[8];
  float v0 = x[row * 768 + tid];
  float v1 = x[row * 768 + 256 + tid];
  float v2 = x[row * 768 + 512 + tid];
  float s = v0 + v1 + v2;
  for (int off = 32; off; off >>= 1) s += __shfl_down(s, off);
  if (lane == 0) sh[w] = s;
  __syncthreads();
  if (tid == 0) sh[4] = (sh[0] + sh[1] + sh[2] + sh[3]) / 768.f;
  __syncthreads();
  float mu = sh[4];
  float d0 = v0 - mu, d1 = v1 - mu, d2 = v2 - mu;
  float q = d0 * d0 + d1 * d1 + d2 * d2;
  for (int off = 32; off; off >>= 1) q += __shfl_down(q, off);
  if (lane == 0) sh[w] = q;
  __syncthreads();
  if (tid == 0) sh[5] = rsqrtf((sh[0] + sh[1] + sh[2] + sh[3]) / 768.f + 1e-5f);
  __syncthreads();
  float rstd = sh[5];
  out[row * 768 + tid]       = d0 * rstd * gam[tid]       + bet[tid];
  out[row * 768 + 256 + tid] = d1 * rstd * gam[256 + tid] + bet[256 + tid];
  out[row * 768 + 512 + tid] = d2 * rstd * gam[512 + tid] + bet[512 + tid];
}

// ============================================================================
extern "C" void kernel_launch(void* const* d_in, const int* in_sizes, int n_in,
                              void* d_out, int out_size, void* d_ws, size_t ws_size,
                              hipStream_t stream)
{
  const float* x     = (const float*)d_in[0];
  const int*   ei    = (const int*)d_in[1];
  const int*   batch = (const int*)d_in[2];
  const float* W[3]   = {(const float*)d_in[3], (const float*)d_in[9],  (const float*)d_in[15]};
  const float* asr[3] = {(const float*)d_in[4], (const float*)d_in[10], (const float*)d_in[16]};
  const float* ads[3] = {(const float*)d_in[5], (const float*)d_in[11], (const float*)d_in[17]};
  const float* bc[3]  = {(const float*)d_in[6], (const float*)d_in[12], (const float*)d_in[18]};
  const float* Wh[3]  = {(const float*)d_in[7], (const float*)d_in[13], (const float*)d_in[19]};
  const float* bh[3]  = {(const float*)d_in[8], (const float*)d_in[14], (const float*)d_in[20]};
  const float* Wm1 = (const float*)d_in[21];
  const float* bm1 = (const float*)d_in[22];
  const float* Wm2 = (const float*)d_in[23];
  const float* bm2 = (const float*)d_in[24];
  const float* lng = (const float*)d_in[25];
  const float* lnb = (const float*)d_in[26];
  float* out = (float*)d_out;

  int Nn = in_sizes[2];        // 5000
  int E  = in_sizes[1] / 2;    // 15000
  int ET = E + Nn;

  // ---- memory plan (~229 MB; R1 proved >=250 available) ----
  // act: single buffer (z-GEMM reads it fully before aggregate2 overwrites).
  // zb (83.9 MB) time-shared: [prep] Wb1/Wht1 then Wb2/Wht2; [layers] z; [MLP] Mt.
  char* base = (char*)d_ws;
  size_t off = 0;
  auto alloc = [&](size_t b) -> char* { char* p = base + off; off = (off + b + 255) & ~(size_t)255; return p; };
  u16*  act   = (u16*)alloc((size_t)5120 * 2048 * 2);      // 21.0
  u16*  Wb0d  = (u16*)alloc((size_t)512  * 8192 * 2);      // 8.4
  u16*  Wht0d = (u16*)alloc((size_t)2048 * 8192 * 2);      // 33.6
  u16*  Ut0   = (u16*)alloc((size_t)8192 * 512  * 2);      // 8.4
  u16*  Ut1   = (u16*)alloc((size_t)8192 * 2048 * 2);      // 33.6
  u16*  Ut2   = (u16*)alloc((size_t)8192 * 2048 * 2);      // 33.6
  u16*  zb    = (u16*)alloc((size_t)5120 * 8192 * 2);      // 83.9
  u16*  xb0   = (u16*)alloc((size_t)5120 * 512 * 2);       // 5.2
  float* wsd  = (float*)alloc((size_t)3 * 8 * 2048 * 4);
  float* bhp  = (float*)alloc((size_t)3 * 2048 * 4);
  float* a_s  = (float*)alloc((size_t)Nn * 4 * 4);
  float* a_d  = (float*)alloc((size_t)Nn * 4 * 4);
  float* psum = (float*)alloc((size_t)Nn * 16 * 4);
  float* alpha= (float*)alloc((size_t)ET * 4 * 4);
  int*  deg   = (int*)alloc((size_t)(Nn + 1) * 4);
  int*  rowst = (int*)alloc((size_t)(Nn + 1) * 4);
  int*  cursor= (int*)alloc((size_t)(Nn + 1) * 4);
  int*  srcs  = (int*)alloc((size_t)ET * 4);
  u16*  g     = (u16*)alloc((size_t)128 * 2048 * 2);
  u16*  g2    = (u16*)alloc((size_t)128 * 2048 * 2);
  float* preln= (float*)alloc((size_t)128 * 768 * 4);

  u16* Wb_sh  = zb;                           // layer-local prep scratch
  u16* Wht_sh = zb + (size_t)2048 * 8192;

  // ---- CSR by dst (self loops appended) + input cast ----
  zero_int<<<(Nn + 255) / 256, 256, 0, stream>>>(deg, Nn);
  count_deg<<<(ET + 255) / 256, 256, 0, stream>>>(ei, E, Nn, deg);
  scan_deg<<<1, 256, 0, stream>>>(deg, rowst, cursor, Nn);
  scatter_edges<<<(ET + 255) / 256, 256, 0, stream>>>(ei, E, Nn, cursor, srcs);
  cast_pad<<<(Nn * 512 + 255) / 256, 256, 0, stream>>>(x, xb0, Nn, 300, 512);

  // ---- weight prep: L0+L1 batched U-GEMM (tail-merge), L2 separate ----
  init_bhp<<<dim3(8, 3), 256, 0, stream>>>(bh[0], bh[1], bh[2], bhp);
  prep_w<<<512, 256, 0, stream>>>(W[0], Wb0d, asr[0], ads[0], wsd, 300, 512);
  transpose_bias<<<dim3(256, 64), 256, 0, stream>>>(Wh[0], Wht0d, bc[0], bhp);
  prep_w<<<2048, 256, 0, stream>>>(W[1], Wb_sh, asr[1], ads[1], wsd + 16384, 2048, 2048);
  transpose_bias<<<dim3(256, 64), 256, 0, stream>>>(Wh[1], Wht_sh, bc[1], bhp + 2048);
  gemm8p_u2<<<320, 512, 0, stream>>>(Wht0d, Wb0d, Ut0, 512,
                                     Wht_sh, Wb_sh, Ut1, 2048, 64);
  prep_w<<<2048, 256, 0, stream>>>(W[2], Wb_sh, asr[2], ads[2], wsd + 32768, 2048, 2048);
  transpose_bias<<<dim3(256, 64), 256, 0, stream>>>(Wh[2], Wht_sh, bc[2], bhp + 4096);
  gemm8p<<<dim3(8, 32), 512, 0, stream>>>(Wht_sh, Wb_sh, Ut2, 8192, 2048, 2048, 8192, 8192, 2048, 1);

  // ---- layer 0 scores ----
  a_score<<<Nn, 256, 0, stream>>>(xb0, wsd, a_s, a_d, 512);

  const u16* actcur = xb0;
  u16* Ut[3] = {Ut0, Ut1, Ut2};
  for (int l = 0; l < 3; ++l) {
    int Fp = (l == 0) ? 512 : 2048;
    edge_softmax<<<(Nn * 4 + 255) / 256, 256, 0, stream>>>(rowst, srcs, a_s, a_d, alpha, Nn);
    gemm8p<<<dim3(32, 20), 512, 0, stream>>>(actcur, Ut[l], zb, Nn, 8192, Fp, Fp, Fp, 8192, 0);
    aggregate2<<<dim3(Nn, 2), 256, 0, stream>>>(zb, alpha, rowst, srcs, bhp + l * 2048, act,
                                                (l < 2) ? 1 : 0,
                                                (l < 2) ? (wsd + (l + 1) * 16384) : nullptr,
                                                psum);
    if (l < 2)
      combine_scores<<<(Nn * 4 + 255) / 256, 256, 0, stream>>>(psum, a_s, a_d, Nn);
    actcur = act;
  }

  // ---- mean pool + MLP + LN (zb dead -> reuse for MLP transposes) ----
  pool_mean<<<128, 256, 0, stream>>>(act, batch, g, Nn);
  u16* Mt1 = zb;
  u16* Mt2 = zb + (size_t)2048 * 2048;
  transpose_cast<<<dim3(64, 64), 256, 0, stream>>>(Wm1, Mt1, 2048, 2048, 2048);
  gemm_bt<<<dim3(16, 1), 256, 0, stream>>>(g, Mt1, nullptr, g2, bm1, 128, 2048, 2048, 1);
  transpose_cast<<<dim3(64, 24), 256, 0, stream>>>(Wm2, Mt2, 2048, 768, 2048);
  gemm_bt<<<dim3(6, 1), 256, 0, stream>>>(g2, Mt2, preln, nullptr, bm2, 128, 768, 2048, 0);
  layernorm_768<<<128, 256, 0, stream>>>(preln, lng, lnb, out);
}

// Round 17
// 1238.469 us; speedup vs baseline: 1.0087x; 1.0087x over previous
//
#include <hip/hip_runtime.h>

typedef unsigned short u16;
typedef __attribute__((ext_vector_type(8))) short short8;
typedef __attribute__((ext_vector_type(4))) short s16x4;
typedef __attribute__((ext_vector_type(4))) float f32x4;

__device__ inline u16 f2bf(float f){
  unsigned int u = __builtin_bit_cast(unsigned int, f);
  u += 0x7fffu + ((u >> 16) & 1u);
  return (u16)(u >> 16);
}
__device__ inline float bf2f(u16 h){
  unsigned int u = ((unsigned int)h) << 16;
  return __builtin_bit_cast(float, u);
}

typedef __attribute__((address_space(1))) const void* as1_t;
typedef __attribute__((address_space(3))) void* as3_t;
__device__ __forceinline__ void gload16(const u16* g, u16* l) {
  __builtin_amdgcn_global_load_lds((as1_t)g, (as3_t)l, 16, 0, 0);
}

#define BARRIER() asm volatile("s_barrier" ::: "memory")
#define VMCNT4()  asm volatile("s_waitcnt vmcnt(4)" ::: "memory")
#define VMCNT0()  asm volatile("s_waitcnt vmcnt(0)" ::: "memory")
#define LGKM0()   asm volatile("s_waitcnt lgkmcnt(0)" ::: "memory")

// ================= shared 8-phase GEMM core (R8-verified: 0 bank conflicts) ==
// ntst=1: non-temporal C stores (streaming output, keep L3 for operands).
__device__ __forceinline__ void gemm_core(
    const u16* __restrict__ A, const u16* __restrict__ B, u16* __restrict__ C,
    int tile_m, int tile_n, int abase, int hoff,
    int M, int K, int lda, int ldb, int ldc, int ntst, u16* lds)
{
  int tid = threadIdx.x, wave = tid >> 6, lane = tid & 63;
  int wm = wave >> 2, wn = wave & 3;
  int NT = K >> 6;

  const u16* sA[2]; const u16* sB[2];
  int dq[2];
#pragma unroll
  for (int q = 0; q < 2; ++q) {
    int row = q * 128 + (tid >> 2);
    int cg  = (tid & 3) ^ ((row >> 1) & 3);
    sA[q] = A + (size_t)(abase + row) * lda + hoff + cg * 8;
    sB[q] = B + (size_t)(tile_n + row) * ldb + hoff + cg * 8;
    dq[q] = q * 4096 + tid * 8;
  }

  int l15 = lane & 15, c4 = lane >> 4;
  int aoff[8], boff[4];
#pragma unroll
  for (int mi = 0; mi < 8; ++mi) {
    int r = wm * 128 + mi * 16 + l15;
    aoff[mi] = r * 32 + ((c4 ^ ((r >> 1) & 3)) * 8);
  }
#pragma unroll
  for (int ni = 0; ni < 4; ++ni) {
    int r = wn * 64 + ni * 16 + l15;
    boff[ni] = r * 32 + ((c4 ^ ((r >> 1) & 3)) * 8);
  }

  f32x4 acc[8][4];
#pragma unroll
  for (int mi = 0; mi < 8; ++mi)
#pragma unroll
    for (int ni = 0; ni < 4; ++ni) { f32x4 z = {0.f,0.f,0.f,0.f}; acc[mi][ni] = z; }

#define DSRA(fa, mb, base) \
  fa[0] = *reinterpret_cast<const short8*>(&lds[(base) + aoff[(mb)+0]]); \
  fa[1] = *reinterpret_cast<const short8*>(&lds[(base) + aoff[(mb)+1]]); \
  fa[2] = *reinterpret_cast<const short8*>(&lds[(base) + aoff[(mb)+2]]); \
  fa[3] = *reinterpret_cast<const short8*>(&lds[(base) + aoff[(mb)+3]]);
#define DSRB(fb, base) \
  fb[0] = *reinterpret_cast<const short8*>(&lds[(base) + boff[0]]); \
  fb[1] = *reinterpret_cast<const short8*>(&lds[(base) + boff[1]]); \
  fb[2] = *reinterpret_cast<const short8*>(&lds[(base) + boff[2]]); \
  fb[3] = *reinterpret_cast<const short8*>(&lds[(base) + boff[3]]);
#define MM16(mb, fa, fb) \
  _Pragma("unroll") for (int mi = 0; mi < 4; ++mi) \
  _Pragma("unroll") for (int ni = 0; ni < 4; ++ni) \
    acc[(mb)+mi][ni] = __builtin_amdgcn_mfma_f32_16x16x32_bf16(fa[mi], fb[ni], acc[(mb)+mi][ni], 0, 0, 0);
#define PH_SYNC() BARRIER(); LGKM0(); __builtin_amdgcn_sched_barrier(0)
#define PRIO1() __builtin_amdgcn_s_setprio(1)
#define PRIO0() __builtin_amdgcn_s_setprio(0)

#pragma unroll
  for (int q = 0; q < 2; ++q) {
    gload16(sA[q],      &lds[0     + dq[q]]);
    gload16(sB[q],      &lds[16384 + dq[q]]);
    gload16(sA[q] + 32, &lds[8192  + dq[q]]);
    gload16(sB[q] + 32, &lds[24576 + dq[q]]);
  }
  VMCNT0();
  BARRIER();

  for (int t = 0; t < NT; ++t) {
    int cb = (t & 1) * 32768;
    int nb = cb ^ 32768;
    bool st = (t + 1) < NT;
    int ke = (t + 1) * 64;
    short8 fa[4], fb0[4], fb1[4];
    DSRA(fa, 0, cb + 0);
    DSRB(fb0, cb + 16384);
    if (st) { gload16(sA[0] + ke, &lds[nb + dq[0]]);
              gload16(sA[1] + ke, &lds[nb + dq[1]]); }
    PH_SYNC(); PRIO1(); MM16(0, fa, fb0); PRIO0();
    BARRIER();
    DSRA(fa, 4, cb + 0);
    if (st) { gload16(sB[0] + ke, &lds[nb + 16384 + dq[0]]);
              gload16(sB[1] + ke, &lds[nb + 16384 + dq[1]]); }
    PH_SYNC(); PRIO1(); MM16(4, fa, fb0); PRIO0();
    if (st) { VMCNT4(); } else { VMCNT0(); }
    BARRIER();
    DSRA(fa, 0, cb + 8192);
    DSRB(fb1, cb + 24576);
    if (st) { gload16(sA[0] + ke + 32, &lds[nb + 8192 + dq[0]]);
              gload16(sA[1] + ke + 32, &lds[nb + 8192 + dq[1]]); }
    PH_SYNC(); PRIO1(); MM16(0, fa, fb1); PRIO0();
    BARRIER();
    DSRA(fa, 4, cb + 8192);
    if (st) { gload16(sB[0] + ke + 32, &lds[nb + 24576 + dq[0]]);
              gload16(sB[1] + ke + 32, &lds[nb + 24576 + dq[1]]); }
    PH_SYNC(); PRIO1(); MM16(4, fa, fb1); PRIO0();
    if (st) { VMCNT4(); }
    BARRIER();
  }

  int rq = (lane >> 4) * 4;
#pragma unroll
  for (int mi = 0; mi < 8; ++mi)
#pragma unroll
    for (int ni = 0; ni < 4; ++ni) {
      int col = tile_n + wn * 64 + ni * 16 + l15;
#pragma unroll
      for (int j = 0; j < 4; ++j) {
        int row = tile_m + wm * 128 + mi * 16 + rq + j;
        if (row < M) {
          u16 v = f2bf(acc[mi][ni][j]);
          if (ntst) __builtin_nontemporal_store(v, &C[(size_t)row * ldc + col]);
          else      C[(size_t)row * ldc + col] = v;
        }
      }
    }
#undef DSRA
#undef DSRB
#undef MM16
#undef PH_SYNC
#undef PRIO1
#undef PRIO0
}

// GEMM wrapper; headed=1 remaps A rows/K-cols per 2048 head blocks;
// xswz=1 applies m204 bijective XCD-chunk swizzle (requires nwg%8==0);
// ntst=1 streams C past L3.
__global__ __launch_bounds__(512, 2) void gemm8p(
    const u16* __restrict__ A, const u16* __restrict__ B, u16* __restrict__ C,
    int M, int N, int K, int lda, int ldb, int ldc, int headed, int xswz, int ntst)
{
  __shared__ alignas(16) u16 lds[65536];
  int gx = gridDim.x;
  int wg = blockIdx.y * gx + blockIdx.x;
  if (xswz) {
    int nwg = gx * gridDim.y;          // caller guarantees nwg % 8 == 0
    int q = nwg >> 3;
    wg = (wg & 7) * q + (wg >> 3);
  }
  int tile_n = (wg % gx) * 256;
  int tile_m = (wg / gx) * 256;
  int hoff  = headed ? ((tile_m >> 11) << 11) : 0;
  int abase = headed ? (tile_m & 2047) : tile_m;
  gemm_core(A, B, C, tile_m, tile_n, abase, hoff, M, K, lda, ldb, ldc, ntst, lds);
}

// batched 2-job headed U-GEMM (tail-merge): job0 N0 (s1 blocks), job1 N1.
__global__ __launch_bounds__(512, 2) void gemm8p_u2(
    const u16* A0, const u16* B0, u16* C0, int N0,
    const u16* A1, const u16* B1, u16* C1, int N1, int s1)
{
  __shared__ alignas(16) u16 lds[65536];
  int flat = blockIdx.x;
  int j = flat >= s1;
  const u16* A = j ? A1 : A0;
  const u16* B = j ? B1 : B0;
  u16*       C = j ? C1 : C0;
  int N = j ? N1 : N0;
  int lbx = flat - (j ? s1 : 0);
  int ntile = N >> 8;
  int tile_n = (lbx % ntile) * 256;
  int tile_m = (lbx / ntile) * 256;
  gemm_core(A, B, C, tile_m, tile_n, tile_m & 2047, (tile_m >> 11) << 11,
            8192, 2048, 8192, 8192, N, 0, lds);
}

// ---------------- prep_w: W f32 -> Wb bf16 AND wsd score table ---------------
__global__ __launch_bounds__(256) void prep_w(
    const float* __restrict__ W, u16* __restrict__ Wb,
    const float* __restrict__ asrc, const float* __restrict__ adst,
    float* __restrict__ wsd, int Fin, int Fp)
{
  int f = blockIdx.x;
  int w = threadIdx.x >> 6, lane = threadIdx.x & 63;
  if (f >= Fin) {   // zero-pad row (L0: rows 300..511)
    s16x4 z = {0,0,0,0};
#pragma unroll
    for (int i = 0; i < 8; ++i)
      *reinterpret_cast<s16x4*>(Wb + (size_t)f * 8192 + w * 2048 + lane * 4 + i * 256) = z;
    if (lane == 0) { wsd[w * Fp + f] = 0.f; wsd[(4 + w) * Fp + f] = 0.f; }
    return;
  }
  const float* wr = W + (size_t)f * 8192 + w * 2048;
  const float* as = asrc + w * 2048;
  const float* ad = adst + w * 2048;
  u16* wb = Wb + (size_t)f * 8192 + w * 2048;
  float ss = 0.f, dd = 0.f;
#pragma unroll
  for (int i = 0; i < 8; ++i) {
    int c = lane * 4 + i * 256;
    f32x4 wv = *reinterpret_cast<const f32x4*>(wr + c);
    f32x4 av = *reinterpret_cast<const f32x4*>(as + c);
    f32x4 dv = *reinterpret_cast<const f32x4*>(ad + c);
    s16x4 ov;
#pragma unroll
    for (int j = 0; j < 4; ++j) {
      ss += wv[j] * av[j]; dd += wv[j] * dv[j];
      ov[j] = (short)f2bf(wv[j]);
    }
    *reinterpret_cast<s16x4*>(wb + c) = ov;
  }
  for (int off = 32; off; off >>= 1) {
    ss += __shfl_down(ss, off);
    dd += __shfl_down(dd, off);
  }
  if (lane == 0) { wsd[w * Fp + f] = ss; wsd[(4 + w) * Fp + f] = dd; }
}

// ------- transpose_bias: Wh[8192,2048] -> Wht[2048,8192] + atomic bc-fold ----
__global__ __launch_bounds__(256) void transpose_bias(
    const float* __restrict__ Wh, u16* __restrict__ Wht,
    const float* __restrict__ bc, float* __restrict__ bhp)
{
  __shared__ float tile[32][33];
  int k0 = blockIdx.x * 32, n0 = blockIdx.y * 32;
  int tx = threadIdx.x & 31, ty = threadIdx.x >> 5;
#pragma unroll
  for (int i = 0; i < 4; ++i)
    tile[ty + i * 8][tx] = Wh[(size_t)(k0 + ty + i * 8) * 2048 + n0 + tx];
  __syncthreads();
#pragma unroll
  for (int i = 0; i < 4; ++i)
    Wht[(size_t)(n0 + ty + i * 8) * 8192 + k0 + tx] = f2bf(tile[tx][ty + i * 8]);
  if (threadIdx.x < 32) {
    float p = 0.f;
#pragma unroll
    for (int kk = 0; kk < 32; ++kk) p += bc[k0 + kk] * tile[kk][threadIdx.x];
    atomicAdd(&bhp[n0 + threadIdx.x], p);
  }
}

__global__ void init_bhp(const float* b0, const float* b1, const float* b2,
                         float* bhp){
  int i = blockIdx.x * 256 + threadIdx.x;
  int l = blockIdx.y;
  if (i < 2048) {
    const float* s = (l == 0) ? b0 : (l == 1 ? b1 : b2);
    bhp[l * 2048 + i] = s[i];
  }
}

// ---------------- transpose_cast (MLP weights) -------------------------------
__global__ __launch_bounds__(256) void transpose_cast(
    const float* __restrict__ W, u16* __restrict__ Wt, int K, int N, int Kpad)
{
  __shared__ float tile[32][33];
  int k0 = blockIdx.x * 32, n0 = blockIdx.y * 32;
  int tx = threadIdx.x & 31, ty = threadIdx.x >> 5;
#pragma unroll
  for (int i = 0; i < 4; ++i) {
    int k = k0 + ty + i * 8;
    float v = 0.f;
    if (k < K && (n0 + tx) < N) v = W[(size_t)k * N + n0 + tx];
    tile[ty + i * 8][tx] = v;
  }
  __syncthreads();
#pragma unroll
  for (int i = 0; i < 4; ++i) {
    int nn = n0 + ty + i * 8;
    if (nn < N) Wt[(size_t)nn * Kpad + k0 + tx] = f2bf(tile[tx][ty + i * 8]);
  }
}

// ---------------- cast with col padding --------------------------------------
__global__ void cast_pad(const float* __restrict__ x, u16* __restrict__ xb,
                         int R, int C, int Cp)
{
  int i = blockIdx.x * 256 + threadIdx.x;
  if (i >= R * Cp) return;
  int r = i / Cp, c = i % Cp;
  xb[i] = f2bf(c < C ? x[(size_t)r * C + c] : 0.f);
}

// ---------------- a_score (layer 0 only) -------------------------------------
__global__ __launch_bounds__(256) void a_score(
    const u16* __restrict__ xb, const float* __restrict__ wsd,
    float* __restrict__ a_s, float* __restrict__ a_d, int Fp)
{
  int n = blockIdx.x, tid = threadIdx.x, lane = tid & 63, w = tid >> 6;
  float s[4] = {0.f,0.f,0.f,0.f}, d[4] = {0.f,0.f,0.f,0.f};
  int f = tid * 8;
  if (f < Fp) {
    short8 v = *reinterpret_cast<const short8*>(xb + (size_t)n * Fp + f);
#pragma unroll
    for (int j = 0; j < 8; ++j) {
      float xv = bf2f((u16)v[j]);
#pragma unroll
      for (int h = 0; h < 4; ++h) {
        s[h] += xv * wsd[h * Fp + f + j];
        d[h] += xv * wsd[(4 + h) * Fp + f + j];
      }
    }
  }
  __shared__ float red[4][8];
#pragma unroll
  for (int h = 0; h < 4; ++h) {
    for (int off = 32; off; off >>= 1) {
      s[h] += __shfl_down(s[h], off);
      d[h] += __shfl_down(d[h], off);
    }
  }
  if (lane == 0) {
#pragma unroll
    for (int h = 0; h < 4; ++h) { red[w][h] = s[h]; red[w][4 + h] = d[h]; }
  }
  __syncthreads();
  if (tid < 8) {
    float t = red[0][tid] + red[1][tid] + red[2][tid] + red[3][tid];
    if (tid < 4) a_s[n * 4 + tid] = t;
    else         a_d[n * 4 + tid - 4] = t;
  }
}

// ---------------- CSR build --------------------------------------------------
__global__ void zero_int(int* p, int n){ int i = blockIdx.x*256+threadIdx.x; if (i < n) p[i] = 0; }

__global__ void count_deg(const int* __restrict__ ei, int E, int Nn, int* __restrict__ deg){
  int e = blockIdx.x*256+threadIdx.x; if (e >= E + Nn) return;
  int d = (e < E) ? ei[E + e] : (e - E);
  atomicAdd(&deg[d], 1);
}

__global__ void scan_deg(const int* __restrict__ deg, int* __restrict__ row_st,
                         int* __restrict__ cursor, int Nn){
  __shared__ int partial[256];
  int tid = threadIdx.x;
  int chunk = (Nn + 255) / 256;
  int start = tid * chunk;
  int sum = 0;
  for (int i = 0; i < chunk; ++i) { int idx = start + i; if (idx < Nn) sum += deg[idx]; }
  partial[tid] = sum;
  __syncthreads();
  if (tid == 0) { int acc = 0; for (int i = 0; i < 256; ++i) { int t = partial[i]; partial[i] = acc; acc += t; } }
  __syncthreads();
  int acc = partial[tid];
  for (int i = 0; i < chunk; ++i) {
    int idx = start + i;
    if (idx < Nn) { row_st[idx] = acc; cursor[idx] = acc; acc += deg[idx]; }
  }
  if (tid == 255) row_st[Nn] = acc;
}

__global__ void scatter_edges(const int* __restrict__ ei, int E, int Nn,
                              int* __restrict__ cursor, int* __restrict__ srcs){
  int e = blockIdx.x*256+threadIdx.x; if (e >= E + Nn) return;
  int s = (e < E) ? ei[e]     : (e - E);
  int d = (e < E) ? ei[E + e] : (e - E);
  int pos = atomicAdd(&cursor[d], 1);
  srcs[pos] = s;
}

// ---------------- per-(node,head) edge softmax -------------------------------
__global__ void edge_softmax(const int* __restrict__ row_st, const int* __restrict__ srcs,
                             const float* __restrict__ a_s, const float* __restrict__ a_d,
                             float* __restrict__ alpha, int Nn){
  int t = blockIdx.x*256+threadIdx.x;
  if (t >= Nn * 4) return;
  int n = t >> 2, hh = t & 3;
  int b = row_st[n], e = row_st[n + 1];
  float ad = a_d[n * 4 + hh];
  float m = -1e30f;
  for (int p = b; p < e; ++p) {
    float x = a_s[srcs[p] * 4 + hh] + ad;
    x = x > 0.f ? x : 0.2f * x;
    alpha[p * 4 + hh] = x;
    m = fmaxf(m, x);
  }
  float ssum = 0.f;
  for (int p = b; p < e; ++p) {
    float ex = expf(alpha[p * 4 + hh] - m);
    alpha[p * 4 + hh] = ex;
    ssum += ex;
  }
  float inv = 1.f / (ssum + 1e-16f);
  for (int p = b; p < e; ++p) alpha[p * 4 + hh] *= inv;
}

// -------- aggregate2: grid (Nn, 2), 256 thr, prefetch distance 2 -------------
__global__ __launch_bounds__(256) void aggregate2(
    const u16* __restrict__ z, const float* __restrict__ alpha,
    const int* __restrict__ row_st, const int* __restrict__ srcs,
    const float* __restrict__ bhp, u16* __restrict__ out, int relu,
    const float* __restrict__ wsd_next, float* __restrict__ psum)
{
  int n = blockIdx.x, half = blockIdx.y, tid = threadIdx.x;
  int c = half * 1024 + tid * 4;
  float acc[4] = {0.f, 0.f, 0.f, 0.f};
  int b = row_st[n], e = row_st[n + 1];

  int s0 = srcs[b];
  const u16* zr = z + (size_t)s0 * 8192 + c;
  s16x4 cv0 = *reinterpret_cast<const s16x4*>(zr);
  s16x4 cv1 = *reinterpret_cast<const s16x4*>(zr + 2048);
  s16x4 cv2 = *reinterpret_cast<const s16x4*>(zr + 4096);
  s16x4 cv3 = *reinterpret_cast<const s16x4*>(zr + 6144);
  float ca0 = alpha[b * 4 + 0], ca1 = alpha[b * 4 + 1];
  float ca2 = alpha[b * 4 + 2], ca3 = alpha[b * 4 + 3];
  s16x4 nv0, nv1, nv2, nv3;
  float na0 = 0.f, na1 = 0.f, na2 = 0.f, na3 = 0.f;
  if (b + 1 < e) {
    int s1 = srcs[b + 1];
    const u16* zr1 = z + (size_t)s1 * 8192 + c;
    nv0 = *reinterpret_cast<const s16x4*>(zr1);
    nv1 = *reinterpret_cast<const s16x4*>(zr1 + 2048);
    nv2 = *reinterpret_cast<const s16x4*>(zr1 + 4096);
    nv3 = *reinterpret_cast<const s16x4*>(zr1 + 6144);
    na0 = alpha[(b + 1) * 4 + 0]; na1 = alpha[(b + 1) * 4 + 1];
    na2 = alpha[(b + 1) * 4 + 2]; na3 = alpha[(b + 1) * 4 + 3];
  }

  for (int p = b; p < e; ++p) {
    s16x4 w0 = cv0, w1 = cv1, w2 = cv2, w3 = cv3;
    float b0 = ca0, b1 = ca1, b2 = ca2, b3 = ca3;
    cv0 = nv0; cv1 = nv1; cv2 = nv2; cv3 = nv3;
    ca0 = na0; ca1 = na1; ca2 = na2; ca3 = na3;
    if (p + 2 < e) {
      int s2 = srcs[p + 2];
      const u16* zr2 = z + (size_t)s2 * 8192 + c;
      nv0 = *reinterpret_cast<const s16x4*>(zr2);
      nv1 = *reinterpret_cast<const s16x4*>(zr2 + 2048);
      nv2 = *reinterpret_cast<const s16x4*>(zr2 + 4096);
      nv3 = *reinterpret_cast<const s16x4*>(zr2 + 6144);
      na0 = alpha[(p + 2) * 4 + 0]; na1 = alpha[(p + 2) * 4 + 1];
      na2 = alpha[(p + 2) * 4 + 2]; na3 = alpha[(p + 2) * 4 + 3];
    }
#pragma unroll
    for (int q = 0; q < 4; ++q)
      acc[q] += b0 * bf2f((u16)w0[q]) + b1 * bf2f((u16)w1[q])
              + b2 * bf2f((u16)w2[q]) + b3 * bf2f((u16)w3[q]);
  }

  float sv[4] = {0.f,0.f,0.f,0.f}, dv[4] = {0.f,0.f,0.f,0.f};
  s16x4 ov;
#pragma unroll
  for (int q = 0; q < 4; ++q) {
    float v = acc[q] + bhp[c + q];
    if (relu) v = fmaxf(v, 0.f);
    ov[q] = (short)f2bf(v);
    if (wsd_next) {
#pragma unroll
      for (int h = 0; h < 4; ++h) {
        sv[h] += v * wsd_next[h * 2048 + c + q];
        dv[h] += v * wsd_next[(4 + h) * 2048 + c + q];
      }
    }
  }
  *reinterpret_cast<s16x4*>(out + (size_t)n * 2048 + c) = ov;
  if (wsd_next) {
    int lane = tid & 63, w = tid >> 6;
    __shared__ float red[4][8];
#pragma unroll
    for (int h = 0; h < 4; ++h) {
      for (int off = 32; off; off >>= 1) {
        sv[h] += __shfl_down(sv[h], off);
        dv[h] += __shfl_down(dv[h], off);
      }
    }
    if (lane == 0) {
#pragma unroll
      for (int h = 0; h < 4; ++h) { red[w][h] = sv[h]; red[w][4 + h] = dv[h]; }
    }
    __syncthreads();
    if (tid < 8) {
      float t = red[0][tid] + red[1][tid] + red[2][tid] + red[3][tid];
      psum[(size_t)n * 16 + half * 8 + tid] = t;
    }
  }
}

// -------- combine partial scores ---------------------------------------------
__global__ void combine_scores(const float* __restrict__ psum,
                               float* __restrict__ a_s, float* __restrict__ a_d,
                               int Nn){
  int i = blockIdx.x * 256 + threadIdx.x;
  if (i >= Nn * 4) return;
  int n = i >> 2, h = i & 3;
  a_s[i] = psum[(size_t)n * 16 + h]     + psum[(size_t)n * 16 + 8 + h];
  a_d[i] = psum[(size_t)n * 16 + 4 + h] + psum[(size_t)n * 16 + 12 + h];
}

// ---------------- mean pool over sorted batch --------------------------------
__global__ __launch_bounds__(256) void pool_mean(
    const u16* __restrict__ hf, const int* __restrict__ batch,
    u16* __restrict__ g, int Nn)
{
  int gid = blockIdx.x, tid = threadIdx.x;
  int s1, s2;
  { int l = 0, h = Nn; while (l < h) { int m = (l + h) >> 1; if (batch[m] < gid) l = m + 1; else h = m; } s1 = l; }
  { int l = 0, h = Nn; while (l < h) { int m = (l + h) >> 1; if (batch[m] < gid + 1) l = m + 1; else h = m; } s2 = l; }
  float inv = 1.f / fmaxf((float)(s2 - s1), 1.f);
  float acc[8];
#pragma unroll
  for (int q = 0; q < 8; ++q) acc[q] = 0.f;
  for (int r = s1; r < s2; ++r) {
    short8 v = *reinterpret_cast<const short8*>(hf + (size_t)r * 2048 + tid * 8);
#pragma unroll
    for (int q = 0; q < 8; ++q) acc[q] += bf2f((u16)v[q]);
  }
  short8 ov;
#pragma unroll
  for (int q = 0; q < 8; ++q) ov[q] = (short)f2bf(acc[q] * inv);
  *reinterpret_cast<short8*>(g + (size_t)gid * 2048 + tid * 8) = ov;
}

// ---------------- 128x128 GEMM (R2 structure; MLP GEMMs) ---------------------
__global__ __launch_bounds__(256) void gemm_bt(
    const u16* __restrict__ A, const u16* __restrict__ B,
    float* __restrict__ Cf, u16* __restrict__ Cb,
    const float* __restrict__ bias, int M, int N, int K, int relu)
{
  __shared__ alignas(16) u16 As[128 * 32];
  __shared__ alignas(16) u16 Bs[128 * 32];
  int tid = threadIdx.x;
  int wave = tid >> 6, lane = tid & 63;
  int wr = wave >> 1, wc = wave & 1;
  int tile_m = blockIdx.y * 128, tile_n = blockIdx.x * 128;

  int sr = wave * 16 + (lane >> 2);
  int sc = (lane & 3) * 8;
  const u16* gA0 = A + (size_t)(tile_m + sr) * K + sc;
  const u16* gA1 = A + (size_t)(tile_m + 64 + sr) * K + sc;
  const u16* gB0 = B + (size_t)(tile_n + sr) * K + sc;
  const u16* gB1 = B + (size_t)(tile_n + 64 + sr) * K + sc;
  u16* lA0 = &As[wave * 512];
  u16* lA1 = &As[2048 + wave * 512];
  u16* lB0 = &Bs[wave * 512];
  u16* lB1 = &Bs[2048 + wave * 512];

  f32x4 acc[4][4];
#pragma unroll
  for (int mi = 0; mi < 4; ++mi)
#pragma unroll
    for (int ni = 0; ni < 4; ++ni) { f32x4 z = {0.f,0.f,0.f,0.f}; acc[mi][ni] = z; }

  int lrow = lane & 15, lk = (lane >> 4) * 8;

  for (int k0 = 0; k0 < K; k0 += 32) {
    gload16(gA0 + k0, lA0);
    gload16(gA1 + k0, lA1);
    gload16(gB0 + k0, lB0);
    gload16(gB1 + k0, lB1);
    __syncthreads();
    short8 af[4], bfr[4];
#pragma unroll
    for (int mi = 0; mi < 4; ++mi)
      af[mi] = *reinterpret_cast<const short8*>(&As[(wr * 64 + mi * 16 + lrow) * 32 + lk]);
#pragma unroll
    for (int ni = 0; ni < 4; ++ni)
      bfr[ni] = *reinterpret_cast<const short8*>(&Bs[(wc * 64 + ni * 16 + lrow) * 32 + lk]);
#pragma unroll
    for (int mi = 0; mi < 4; ++mi)
#pragma unroll
      for (int ni = 0; ni < 4; ++ni)
        acc[mi][ni] = __builtin_amdgcn_mfma_f32_16x16x32_bf16(af[mi], bfr[ni], acc[mi][ni], 0, 0, 0);
    __syncthreads();
  }

  int rquad = (lane >> 4) * 4;
#pragma unroll
  for (int mi = 0; mi < 4; ++mi)
#pragma unroll
    for (int ni = 0; ni < 4; ++ni) {
      int col = tile_n + wc * 64 + ni * 16 + lrow;
      float bv = bias ? bias[col] : 0.f;
#pragma unroll
      for (int j = 0; j < 4; ++j) {
        int row = tile_m + wr * 64 + mi * 16 + rquad + j;
        if (row < M) {
          float v = acc[mi][ni][j] + bv;
          if (relu) v = fmaxf(v, 0.f);
          if (Cb) Cb[(size_t)row * N + col] = f2bf(v);
          else    Cf[(size_t)row * N + col] = v;
        }
      }
    }
}

// ---------------- layernorm over 768 ----------------------------------------
__global__ __launch_bounds__(256) void layernorm_768(
    const float* __restrict__ x, const float* __restrict__ gam,
    const float* __restrict__ bet, float* __restrict__ out)
{
  int row = blockIdx.x, tid = threadIdx.x, lane = tid & 63, w = tid >> 6;
  __shared__ float sh[8];
  float v0 = x[row * 768 + tid];
  float v1 = x[row * 768 + 256 + tid];
  float v2 = x[row * 768 + 512 + tid];
  float s = v0 + v1 + v2;
  for (int off = 32; off; off >>= 1) s += __shfl_down(s, off);
  if (lane == 0) sh[w] = s;
  __syncthreads();
  if (tid == 0) sh[4] = (sh[0] + sh[1] + sh[2] + sh[3]) / 768.f;
  __syncthreads();
  float mu = sh[4];
  float d0 = v0 - mu, d1 = v1 - mu, d2 = v2 - mu;
  float q = d0 * d0 + d1 * d1 + d2 * d2;
  for (int off = 32; off; off >>= 1) q += __shfl_down(q, off);
  if (lane == 0) sh[w] = q;
  __syncthreads();
  if (tid == 0) sh[5] = rsqrtf((sh[0] + sh[1] + sh[2] + sh[3]) / 768.f + 1e-5f);
  __syncthreads();
  float rstd = sh[5];
  out[row * 768 + tid]       = d0 * rstd * gam[tid]       + bet[tid];
  out[row * 768 + 256 + tid] = d1 * rstd * gam[256 + tid] + bet[256 + tid];
  out[row * 768 + 512 + tid] = d2 * rstd * gam[512 + tid] + bet[512 + tid];
}

// ============================================================================
extern "C" void kernel_launch(void* const* d_in, const int* in_sizes, int n_in,
                              void* d_out, int out_size, void* d_ws, size_t ws_size,
                              hipStream_t stream)
{
  const float* x     = (const float*)d_in[0];
  const int*   ei    = (const int*)d_in[1];
  const int*   batch = (const int*)d_in[2];
  const float* W[3]   = {(const float*)d_in[3], (const float*)d_in[9],  (const float*)d_in[15]};
  const float* asr[3] = {(const float*)d_in[4], (const float*)d_in[10], (const float*)d_in[16]};
  const float* ads[3] = {(const float*)d_in[5], (const float*)d_in[11], (const float*)d_in[17]};
  const float* bc[3]  = {(const float*)d_in[6], (const float*)d_in[12], (const float*)d_in[18]};
  const float* Wh[3]  = {(const float*)d_in[7], (const float*)d_in[13], (const float*)d_in[19]};
  const float* bh[3]  = {(const float*)d_in[8], (const float*)d_in[14], (const float*)d_in[20]};
  const float* Wm1 = (const float*)d_in[21];
  const float* bm1 = (const float*)d_in[22];
  const float* Wm2 = (const float*)d_in[23];
  const float* bm2 = (const float*)d_in[24];
  const float* lng = (const float*)d_in[25];
  const float* lnb = (const float*)d_in[26];
  float* out = (float*)d_out;

  int Nn = in_sizes[2];        // 5000
  int E  = in_sizes[1] / 2;    // 15000
  int ET = E + Nn;

  // ---- memory plan (~229 MB) ----
  char* base = (char*)d_ws;
  size_t off = 0;
  auto alloc = [&](size_t b) -> char* { char* p = base + off; off = (off + b + 255) & ~(size_t)255; return p; };
  u16*  act   = (u16*)alloc((size_t)5120 * 2048 * 2);
  u16*  Wb0d  = (u16*)alloc((size_t)512  * 8192 * 2);
  u16*  Wht0d = (u16*)alloc((size_t)2048 * 8192 * 2);
  u16*  Ut0   = (u16*)alloc((size_t)8192 * 512  * 2);
  u16*  Ut1   = (u16*)alloc((size_t)8192 * 2048 * 2);
  u16*  Ut2   = (u16*)alloc((size_t)8192 * 2048 * 2);
  u16*  zb    = (u16*)alloc((size_t)5120 * 8192 * 2);
  u16*  xb0   = (u16*)alloc((size_t)5120 * 512 * 2);
  float* wsd  = (float*)alloc((size_t)3 * 8 * 2048 * 4);
  float* bhp  = (float*)alloc((size_t)3 * 2048 * 4);
  float* a_s  = (float*)alloc((size_t)Nn * 4 * 4);
  float* a_d  = (float*)alloc((size_t)Nn * 4 * 4);
  float* psum = (float*)alloc((size_t)Nn * 16 * 4);
  float* alpha= (float*)alloc((size_t)ET * 4 * 4);
  int*  deg   = (int*)alloc((size_t)(Nn + 1) * 4);
  int*  rowst = (int*)alloc((size_t)(Nn + 1) * 4);
  int*  cursor= (int*)alloc((size_t)(Nn + 1) * 4);
  int*  srcs  = (int*)alloc((size_t)ET * 4);
  u16*  g     = (u16*)alloc((size_t)128 * 2048 * 2);
  u16*  g2    = (u16*)alloc((size_t)128 * 2048 * 2);
  float* preln= (float*)alloc((size_t)128 * 768 * 4);

  u16* Wb_sh  = zb;
  u16* Wht_sh = zb + (size_t)2048 * 8192;

  // ---- CSR by dst (self loops appended) + input cast ----
  zero_int<<<(Nn + 255) / 256, 256, 0, stream>>>(deg, Nn);
  count_deg<<<(ET + 255) / 256, 256, 0, stream>>>(ei, E, Nn, deg);
  scan_deg<<<1, 256, 0, stream>>>(deg, rowst, cursor, Nn);
  scatter_edges<<<(ET + 255) / 256, 256, 0, stream>>>(ei, E, Nn, cursor, srcs);
  cast_pad<<<(Nn * 512 + 255) / 256, 256, 0, stream>>>(x, xb0, Nn, 300, 512);

  // ---- weight prep: L0+L1 batched U-GEMM (tail-merge), L2 separate ----
  init_bhp<<<dim3(8, 3), 256, 0, stream>>>(bh[0], bh[1], bh[2], bhp);
  prep_w<<<512, 256, 0, stream>>>(W[0], Wb0d, asr[0], ads[0], wsd, 300, 512);
  transpose_bias<<<dim3(256, 64), 256, 0, stream>>>(Wh[0], Wht0d, bc[0], bhp);
  prep_w<<<2048, 256, 0, stream>>>(W[1], Wb_sh, asr[1], ads[1], wsd + 16384, 2048, 2048);
  transpose_bias<<<dim3(256, 64), 256, 0, stream>>>(Wh[1], Wht_sh, bc[1], bhp + 2048);
  gemm8p_u2<<<320, 512, 0, stream>>>(Wht0d, Wb0d, Ut0, 512,
                                     Wht_sh, Wb_sh, Ut1, 2048, 64);
  prep_w<<<2048, 256, 0, stream>>>(W[2], Wb_sh, asr[2], ads[2], wsd + 32768, 2048, 2048);
  transpose_bias<<<dim3(256, 64), 256, 0, stream>>>(Wh[2], Wht_sh, bc[2], bhp + 4096);
  gemm8p<<<dim3(8, 32), 512, 0, stream>>>(Wht_sh, Wb_sh, Ut2, 8192, 2048, 2048, 8192, 8192, 2048, 1, 0, 0);

  // ---- layer 0 scores ----
  a_score<<<Nn, 256, 0, stream>>>(xb0, wsd, a_s, a_d, 512);

  const u16* actcur = xb0;
  u16* Ut[3] = {Ut0, Ut1, Ut2};
  for (int l = 0; l < 3; ++l) {
    // L0: K=320 (Ut0 cols 300.. are zero; padded lda/ldb=512) — NT=5 is fine.
    int Kz  = (l == 0) ? 320 : 2048;
    int ldz = (l == 0) ? 512 : 2048;
    edge_softmax<<<(Nn * 4 + 255) / 256, 256, 0, stream>>>(rowst, srcs, a_s, a_d, alpha, Nn);
    gemm8p<<<dim3(32, 20), 512, 0, stream>>>(actcur, Ut[l], zb, Nn, 8192, Kz, ldz, ldz, 8192, 0, 1, 1);
    aggregate2<<<dim3(Nn, 2), 256, 0, stream>>>(zb, alpha, rowst, srcs, bhp + l * 2048, act,
                                                (l < 2) ? 1 : 0,
                                                (l < 2) ? (wsd + (l + 1) * 16384) : nullptr,
                                                psum);
    if (l < 2)
      combine_scores<<<(Nn * 4 + 255) / 256, 256, 0, stream>>>(psum, a_s, a_d, Nn);
    actcur = act;
  }

  // ---- mean pool + MLP + LN (zb dead -> reuse for MLP transposes) ----
  pool_mean<<<128, 256, 0, stream>>>(act, batch, g, Nn);
  u16* Mt1 = zb;
  u16* Mt2 = zb + (size_t)2048 * 2048;
  transpose_cast<<<dim3(64, 64), 256, 0, stream>>>(Wm1, Mt1, 2048, 2048, 2048);
  gemm_bt<<<dim3(16, 1), 256, 0, stream>>>(g, Mt1, nullptr, g2, bm1, 128, 2048, 2048, 1);
  transpose_cast<<<dim3(64, 24), 256, 0, stream>>>(Wm2, Mt2, 2048, 768, 2048);
  gemm_bt<<<dim3(6, 1), 256, 0, stream>>>(g2, Mt2, preln, nullptr, bm2, 128, 768, 2048, 0);
  layernorm_768<<<128, 256, 0, stream>>>(preln, lng, lnb, out);
}